// Round 1
// baseline (443.615 us; speedup 1.0000x reference)
//
#include <hip/hip_runtime.h>

#define NN 50000
#define EE 800000
#define ET 850000   // EE + NN self loops
#define NB 196      // ceil(NN/256)

// ---------------- counting sort: histogram ----------------
__global__ void k_hist(const int* __restrict__ ei, int* __restrict__ cnt) {
    int e = blockIdx.x * 256 + threadIdx.x;
    if (e >= ET) return;
    int d = (e < EE) ? ei[EE + e] : (e - EE);
    atomicAdd(&cnt[d], 1);
}

// per-block inclusive scan of cnt -> rowstart[i+1] (local), blocksum[b]
__global__ void k_scan1(const int* __restrict__ cnt, int* __restrict__ rowstart,
                        int* __restrict__ blocksum) {
    __shared__ int sm0[256], sm1[256];
    int t = threadIdx.x;
    int i = blockIdx.x * 256 + t;
    int v = (i < NN) ? cnt[i] : 0;
    sm0[t] = v;
    __syncthreads();
    int* a = sm0; int* b = sm1;
    for (int off = 1; off < 256; off <<= 1) {
        int x = a[t] + ((t >= off) ? a[t - off] : 0);
        b[t] = x;
        __syncthreads();
        int* tmp = a; a = b; b = tmp;
    }
    if (i < NN) rowstart[i + 1] = a[t];
    if (t == 255) blocksum[blockIdx.x] = a[255];
}

// single-block exclusive scan of blocksum (NB entries)
__global__ void k_scan2(int* __restrict__ blocksum) {
    __shared__ int sm0[256], sm1[256];
    int t = threadIdx.x;
    int v = (t < NB) ? blocksum[t] : 0;
    sm0[t] = v;
    __syncthreads();
    int* a = sm0; int* b = sm1;
    for (int off = 1; off < 256; off <<= 1) {
        int x = a[t] + ((t >= off) ? a[t - off] : 0);
        b[t] = x;
        __syncthreads();
        int* tmp = a; a = b; b = tmp;
    }
    if (t < NB) blocksum[t] = a[t] - v;   // exclusive
}

__global__ void k_scan3(int* __restrict__ rowstart, const int* __restrict__ blocksum) {
    int t = threadIdx.x;
    int i = blockIdx.x * 256 + t;
    if (i < NN) rowstart[i + 1] += blocksum[blockIdx.x];
    if (i == 0) rowstart[0] = 0;
}

__global__ void k_next(const int* __restrict__ rowstart, int* __restrict__ nxt) {
    int i = blockIdx.x * 256 + threadIdx.x;
    if (i < NN) nxt[i] = rowstart[i];
}

__global__ void k_scatter(const int* __restrict__ ei, int* __restrict__ nxt,
                          int* __restrict__ srcs) {
    int e = blockIdx.x * 256 + threadIdx.x;
    if (e >= ET) return;
    int s, d;
    if (e < EE) { s = ei[e]; d = ei[EE + e]; }
    else        { s = e - EE; d = s; }
    int pos = atomicAdd(&nxt[d], 1);
    srcs[pos] = s;
}

// ---------------- layer 1 node GEMM: h1 = [x|topo] @ W1, plus attention logits ----
__global__ __launch_bounds__(256) void k_gemm1(
    const float* __restrict__ x, const float* __restrict__ topo,
    const float* __restrict__ W1, const float* __restrict__ a_src,
    const float* __restrict__ a_dst,
    float* __restrict__ h1, float* __restrict__ alsrc, float* __restrict__ aldst) {
    __shared__ float4 Ws[128 * 16];   // 128 x 64 floats
    for (int i = threadIdx.x; i < 2048; i += 256) Ws[i] = ((const float4*)W1)[i];
    __syncthreads();
    int n = blockIdx.x * 256 + threadIdx.x;
    if (n >= NN) return;
    float acc[64];
    #pragma unroll
    for (int c = 0; c < 64; c++) acc[c] = 0.f;
    const float4* xr = (const float4*)(x + (size_t)n * 120);
    const float4* tr = (const float4*)(topo + (size_t)n * 8);
    for (int k4 = 0; k4 < 32; k4++) {
        float4 xv4 = (k4 < 30) ? xr[k4] : tr[k4 - 30];
        float xs[4] = {xv4.x, xv4.y, xv4.z, xv4.w};
        #pragma unroll
        for (int kk = 0; kk < 4; kk++) {
            float xv = xs[kk];
            int k = k4 * 4 + kk;
            #pragma unroll
            for (int c4 = 0; c4 < 16; c4++) {
                float4 w = Ws[k * 16 + c4];
                acc[c4 * 4 + 0] += xv * w.x;
                acc[c4 * 4 + 1] += xv * w.y;
                acc[c4 * 4 + 2] += xv * w.z;
                acc[c4 * 4 + 3] += xv * w.w;
            }
        }
    }
    float4* hr = (float4*)(h1 + (size_t)n * 64);
    #pragma unroll
    for (int c4 = 0; c4 < 16; c4++)
        hr[c4] = make_float4(acc[c4 * 4], acc[c4 * 4 + 1], acc[c4 * 4 + 2], acc[c4 * 4 + 3]);
    #pragma unroll
    for (int h = 0; h < 8; h++) {
        float s1 = 0.f, s2 = 0.f;
        #pragma unroll
        for (int dd = 0; dd < 8; dd++) {
            float hv = acc[h * 8 + dd];
            s1 += hv * a_src[h * 8 + dd];
            s2 += hv * a_dst[h * 8 + dd];
        }
        alsrc[n * 8 + h] = s1;
        aldst[n * 8 + h] = s2;
    }
}

// ---------------- layer 1 aggregation: one wave per destination node -------------
__global__ __launch_bounds__(256) void k_agg1(
    const int* __restrict__ rowstart, const int* __restrict__ srcs,
    const float* __restrict__ alsrc, const float* __restrict__ aldst,
    const float* __restrict__ h1, const float* __restrict__ b1,
    float* __restrict__ hout) {
    int wave = threadIdx.x >> 6;
    int lane = threadIdx.x & 63;
    int d = blockIdx.x * 4 + wave;
    if (d >= NN) return;
    int c = lane;
    int h = lane >> 3;
    float adst = aldst[d * 8 + h];
    int jb = rowstart[d], je = rowstart[d + 1];
    float ssum = 0.f, acc = 0.f;
    for (int j = jb; j < je; j++) {
        int s = srcs[j];
        float ea = alsrc[s * 8 + h] + adst;
        float lr = (ea > 0.f) ? ea : 0.2f * ea;
        float p = __expf(lr);
        ssum += p;
        acc += p * h1[(size_t)s * 64 + c];
    }
    float val = acc / ssum + b1[c];
    val = (val > 0.f) ? val : (__expf(val) - 1.f);   // ELU
    hout[(size_t)d * 64 + c] = val;
}

// ---------------- layer 2 node GEMM ---------------------------------------------
__global__ __launch_bounds__(256) void k_gemm2(
    const float* __restrict__ hout, const float* __restrict__ W2,
    const float* __restrict__ a_src2, const float* __restrict__ a_dst2,
    float* __restrict__ h2, float* __restrict__ al2s, float* __restrict__ al2d) {
    __shared__ float4 Ws[640];        // 64 x 40 floats
    __shared__ float as2[40], ad2[40];
    for (int i = threadIdx.x; i < 640; i += 256) Ws[i] = ((const float4*)W2)[i];
    if (threadIdx.x < 40) {
        as2[threadIdx.x] = a_src2[threadIdx.x];
        ad2[threadIdx.x] = a_dst2[threadIdx.x];
    }
    __syncthreads();
    int n = blockIdx.x * 256 + threadIdx.x;
    if (n >= NN) return;
    float acc[40];
    #pragma unroll
    for (int c = 0; c < 40; c++) acc[c] = 0.f;
    const float4* hr = (const float4*)(hout + (size_t)n * 64);
    for (int k4 = 0; k4 < 16; k4++) {
        float4 hv4 = hr[k4];
        float hs[4] = {hv4.x, hv4.y, hv4.z, hv4.w};
        #pragma unroll
        for (int kk = 0; kk < 4; kk++) {
            float hv = hs[kk];
            int k = k4 * 4 + kk;
            #pragma unroll
            for (int c4 = 0; c4 < 10; c4++) {
                float4 w = Ws[k * 10 + c4];
                acc[c4 * 4 + 0] += hv * w.x;
                acc[c4 * 4 + 1] += hv * w.y;
                acc[c4 * 4 + 2] += hv * w.z;
                acc[c4 * 4 + 3] += hv * w.w;
            }
        }
    }
    float s1 = 0.f, s2 = 0.f;
    #pragma unroll
    for (int c = 0; c < 40; c++) { s1 += acc[c] * as2[c]; s2 += acc[c] * ad2[c]; }
    al2s[n] = s1;
    al2d[n] = s2;
    float4* h2r = (float4*)(h2 + (size_t)n * 40);
    #pragma unroll
    for (int c4 = 0; c4 < 10; c4++)
        h2r[c4] = make_float4(acc[c4 * 4], acc[c4 * 4 + 1], acc[c4 * 4 + 2], acc[c4 * 4 + 3]);
}

// ---------------- layer 2 aggregation + fused log_softmax -----------------------
__global__ __launch_bounds__(256) void k_agg2(
    const int* __restrict__ rowstart, const int* __restrict__ srcs,
    const float* __restrict__ al2s, const float* __restrict__ al2d,
    const float* __restrict__ h2, const float* __restrict__ b2,
    float* __restrict__ out) {
    int wave = threadIdx.x >> 6;
    int lane = threadIdx.x & 63;
    int d = blockIdx.x * 4 + wave;
    if (d >= NN) return;
    int c = lane;
    float adst = al2d[d];
    int jb = rowstart[d], je = rowstart[d + 1];
    float ssum = 0.f, acc = 0.f;
    for (int j = jb; j < je; j++) {
        int s = srcs[j];
        float ea = al2s[s] + adst;
        float lr = (ea > 0.f) ? ea : 0.2f * ea;
        float p = __expf(lr);
        ssum += p;
        if (c < 40) acc += p * h2[(size_t)s * 40 + c];
    }
    float o = (c < 40) ? (acc / ssum + b2[c]) : -3.0e38f;
    float m = o;
    #pragma unroll
    for (int off = 32; off; off >>= 1) m = fmaxf(m, __shfl_xor(m, off, 64));
    float t = (c < 40) ? __expf(o - m) : 0.f;
    float sum = t;
    #pragma unroll
    for (int off = 32; off; off >>= 1) sum += __shfl_xor(sum, off, 64);
    if (c < 40) out[(size_t)d * 40 + c] = o - m - __logf(sum);
}

extern "C" void kernel_launch(void* const* d_in, const int* in_sizes, int n_in,
                              void* d_out, int out_size, void* d_ws, size_t ws_size,
                              hipStream_t stream) {
    (void)in_sizes; (void)n_in; (void)out_size; (void)ws_size;
    const float* x    = (const float*)d_in[0];
    const float* topo = (const float*)d_in[1];
    const int*   ei   = (const int*)d_in[2];
    const float* W1   = (const float*)d_in[3];
    const float* as1  = (const float*)d_in[4];
    const float* ad1  = (const float*)d_in[5];
    const float* b1   = (const float*)d_in[6];
    const float* W2   = (const float*)d_in[7];
    const float* as2  = (const float*)d_in[8];
    const float* ad2  = (const float*)d_in[9];
    const float* b2   = (const float*)d_in[10];
    float* out = (float*)d_out;

    char* ws = (char*)d_ws;
    size_t off = 0;
    auto alloc = [&](size_t bytes) {
        void* p = ws + off;
        off += (bytes + 255) / 256 * 256;
        return p;
    };
    int* rowstart  = (int*)alloc((NN + 1) * 4);
    int* cnt       = (int*)alloc(NN * 4);        // doubles as "next" for scatter
    int* blocksum  = (int*)alloc(256 * 4);
    int* srcs      = (int*)alloc(ET * 4);
    float* alsrc1  = (float*)alloc((size_t)NN * 8 * 4);
    float* aldst1  = (float*)alloc((size_t)NN * 8 * 4);
    float* al2s    = (float*)alloc(NN * 4);
    float* al2d    = (float*)alloc(NN * 4);
    float* h1      = (float*)alloc((size_t)NN * 64 * 4);
    float* hout    = (float*)alloc((size_t)NN * 64 * 4);
    float* h2      = h1;   // alias: h1 dead after k_agg1

    hipMemsetAsync(cnt, 0, NN * 4, stream);
    int egrid = (ET + 255) / 256;
    k_hist   <<<egrid, 256, 0, stream>>>(ei, cnt);
    k_scan1  <<<NB,    256, 0, stream>>>(cnt, rowstart, blocksum);
    k_scan2  <<<1,     256, 0, stream>>>(blocksum);
    k_scan3  <<<NB,    256, 0, stream>>>(rowstart, blocksum);
    k_next   <<<NB,    256, 0, stream>>>(rowstart, cnt);
    k_scatter<<<egrid, 256, 0, stream>>>(ei, cnt, srcs);
    k_gemm1  <<<NB,    256, 0, stream>>>(x, topo, W1, as1, ad1, h1, alsrc1, aldst1);
    k_agg1   <<<(NN + 3) / 4, 256, 0, stream>>>(rowstart, srcs, alsrc1, aldst1, h1, b1, hout);
    k_gemm2  <<<NB,    256, 0, stream>>>(hout, W2, as2, ad2, h2, al2s, al2d);
    k_agg2   <<<(NN + 3) / 4, 256, 0, stream>>>(rowstart, srcs, al2s, al2d, h2, b2, out);
}

// Round 2
// 322.626 us; speedup vs baseline: 1.3750x; 1.3750x over previous
//
#include <hip/hip_runtime.h>

#define NN 50000
#define EE 800000
#define ET 850000   // EE + NN self loops
#define NB 196      // ceil(NN/256)
#define NB1 196     // ceil((NN+1)/256) = 196 (50001 <= 50176)

// cnt[i] = 1 (accounts for the self loop)
__global__ void k_initcnt(int* __restrict__ cnt) {
    int i = blockIdx.x * 256 + threadIdx.x;
    if (i < NN) cnt[i] = 1;
}

// histogram of real edge destinations
__global__ void k_hist(const int* __restrict__ ei, int* __restrict__ cnt) {
    int e = blockIdx.x * 256 + threadIdx.x;
    if (e >= EE) return;
    atomicAdd(&cnt[ei[EE + e]], 1);
}

// per-block inclusive scan of cnt -> rowstart[i+1] (block-local), blocksum[b]
__global__ void k_scan1(const int* __restrict__ cnt, int* __restrict__ rowstart,
                        int* __restrict__ blocksum) {
    __shared__ int sm0[256], sm1[256];
    int t = threadIdx.x;
    int i = blockIdx.x * 256 + t;
    int v = (i < NN) ? cnt[i] : 0;
    sm0[t] = v;
    __syncthreads();
    int* a = sm0; int* b = sm1;
    for (int off = 1; off < 256; off <<= 1) {
        int x = a[t] + ((t >= off) ? a[t - off] : 0);
        b[t] = x;
        __syncthreads();
        int* tmp = a; a = b; b = tmp;
    }
    if (i < NN) rowstart[i + 1] = a[t];
    if (t == 255) blocksum[blockIdx.x] = a[255];
}

// single-block exclusive scan of blocksum (NB entries)
__global__ void k_scan2(int* __restrict__ blocksum) {
    __shared__ int sm0[256], sm1[256];
    int t = threadIdx.x;
    int v = (t < NB) ? blocksum[t] : 0;
    sm0[t] = v;
    __syncthreads();
    int* a = sm0; int* b = sm1;
    for (int off = 1; off < 256; off <<= 1) {
        int x = a[t] + ((t >= off) ? a[t - off] : 0);
        b[t] = x;
        __syncthreads();
        int* tmp = a; a = b; b = tmp;
    }
    if (t < NB) blocksum[t] = a[t] - v;   // exclusive
}

// rowstart[i] -> final; plant self-loop at segment slot 0; init scatter cursor
__global__ void k_finalize(int* __restrict__ rowstart, const int* __restrict__ blocksum,
                           int* __restrict__ nxt, int* __restrict__ srcs) {
    int i = blockIdx.x * 256 + threadIdx.x;
    if (i > NN) return;
    int fin = (i == 0) ? 0 : rowstart[i] + blocksum[(i - 1) >> 8];
    rowstart[i] = fin;
    if (i < NN) {
        srcs[fin] = i;        // self loop occupies slot 0 of segment i
        nxt[i] = fin + 1;
    }
}

__global__ void k_scatter(const int* __restrict__ ei, int* __restrict__ nxt,
                          int* __restrict__ srcs) {
    int e = blockIdx.x * 256 + threadIdx.x;
    if (e >= EE) return;
    int s = ei[e], d = ei[EE + e];
    int pos = atomicAdd(&nxt[d], 1);
    srcs[pos] = s;
}

// ---------------- layer 1 node GEMM: h1 = [x|topo] @ W1, plus attention logits ----
__global__ __launch_bounds__(256) void k_gemm1(
    const float* __restrict__ x, const float* __restrict__ topo,
    const float* __restrict__ W1, const float* __restrict__ a_src,
    const float* __restrict__ a_dst,
    float* __restrict__ h1, float* __restrict__ alsrc, float* __restrict__ aldst) {
    __shared__ float4 Ws[128 * 16];   // 128 x 64 floats
    for (int i = threadIdx.x; i < 2048; i += 256) Ws[i] = ((const float4*)W1)[i];
    __syncthreads();
    int n = blockIdx.x * 256 + threadIdx.x;
    if (n >= NN) return;
    float acc[64];
    #pragma unroll
    for (int c = 0; c < 64; c++) acc[c] = 0.f;
    const float4* xr = (const float4*)(x + (size_t)n * 120);
    const float4* tr = (const float4*)(topo + (size_t)n * 8);
    for (int k4 = 0; k4 < 32; k4++) {
        float4 xv4 = (k4 < 30) ? xr[k4] : tr[k4 - 30];
        float xs[4] = {xv4.x, xv4.y, xv4.z, xv4.w};
        #pragma unroll
        for (int kk = 0; kk < 4; kk++) {
            float xv = xs[kk];
            int k = k4 * 4 + kk;
            #pragma unroll
            for (int c4 = 0; c4 < 16; c4++) {
                float4 w = Ws[k * 16 + c4];
                acc[c4 * 4 + 0] += xv * w.x;
                acc[c4 * 4 + 1] += xv * w.y;
                acc[c4 * 4 + 2] += xv * w.z;
                acc[c4 * 4 + 3] += xv * w.w;
            }
        }
    }
    float4* hr = (float4*)(h1 + (size_t)n * 64);
    #pragma unroll
    for (int c4 = 0; c4 < 16; c4++)
        hr[c4] = make_float4(acc[c4 * 4], acc[c4 * 4 + 1], acc[c4 * 4 + 2], acc[c4 * 4 + 3]);
    #pragma unroll
    for (int h = 0; h < 8; h++) {
        float s1 = 0.f, s2 = 0.f;
        #pragma unroll
        for (int dd = 0; dd < 8; dd++) {
            float hv = acc[h * 8 + dd];
            s1 += hv * a_src[h * 8 + dd];
            s2 += hv * a_dst[h * 8 + dd];
        }
        alsrc[n * 8 + h] = s1;
        aldst[n * 8 + h] = s2;
    }
}

// ---------------- layer 1 aggregation: one wave per destination node -------------
__global__ __launch_bounds__(256) void k_agg1(
    const int* __restrict__ rowstart, const int* __restrict__ srcs,
    const float* __restrict__ alsrc, const float* __restrict__ aldst,
    const float* __restrict__ h1, const float* __restrict__ b1,
    float* __restrict__ hout) {
    int wave = threadIdx.x >> 6;
    int lane = threadIdx.x & 63;
    int d = blockIdx.x * 4 + wave;
    if (d >= NN) return;
    int c = lane;
    int h = lane >> 3;
    float adst = aldst[d * 8 + h];
    int jb = rowstart[d], je = rowstart[d + 1];
    float ssum = 0.f, acc = 0.f;
    int j = jb;
    for (; j + 4 <= je; j += 4) {
        int s0 = srcs[j], s1 = srcs[j + 1], s2 = srcs[j + 2], s3 = srcs[j + 3];
        float e0 = alsrc[s0 * 8 + h] + adst;
        float e1 = alsrc[s1 * 8 + h] + adst;
        float e2 = alsrc[s2 * 8 + h] + adst;
        float e3 = alsrc[s3 * 8 + h] + adst;
        float p0 = __expf(fmaxf(e0, 0.2f * e0));
        float p1 = __expf(fmaxf(e1, 0.2f * e1));
        float p2 = __expf(fmaxf(e2, 0.2f * e2));
        float p3 = __expf(fmaxf(e3, 0.2f * e3));
        float v0 = h1[(size_t)s0 * 64 + c];
        float v1 = h1[(size_t)s1 * 64 + c];
        float v2 = h1[(size_t)s2 * 64 + c];
        float v3 = h1[(size_t)s3 * 64 + c];
        ssum += (p0 + p1) + (p2 + p3);
        acc += p0 * v0 + p1 * v1 + p2 * v2 + p3 * v3;
    }
    for (; j < je; j++) {
        int s = srcs[j];
        float ea = alsrc[s * 8 + h] + adst;
        float p = __expf(fmaxf(ea, 0.2f * ea));
        ssum += p;
        acc += p * h1[(size_t)s * 64 + c];
    }
    float val = acc / ssum + b1[c];
    val = (val > 0.f) ? val : (__expf(val) - 1.f);   // ELU
    hout[(size_t)d * 64 + c] = val;
}

// ---------------- layer 2 node GEMM ---------------------------------------------
__global__ __launch_bounds__(256) void k_gemm2(
    const float* __restrict__ hout, const float* __restrict__ W2,
    const float* __restrict__ a_src2, const float* __restrict__ a_dst2,
    float* __restrict__ h2, float* __restrict__ al2s, float* __restrict__ al2d) {
    __shared__ float4 Ws[640];        // 64 x 40 floats
    __shared__ float as2[40], ad2[40];
    for (int i = threadIdx.x; i < 640; i += 256) Ws[i] = ((const float4*)W2)[i];
    if (threadIdx.x < 40) {
        as2[threadIdx.x] = a_src2[threadIdx.x];
        ad2[threadIdx.x] = a_dst2[threadIdx.x];
    }
    __syncthreads();
    int n = blockIdx.x * 256 + threadIdx.x;
    if (n >= NN) return;
    float acc[40];
    #pragma unroll
    for (int c = 0; c < 40; c++) acc[c] = 0.f;
    const float4* hr = (const float4*)(hout + (size_t)n * 64);
    for (int k4 = 0; k4 < 16; k4++) {
        float4 hv4 = hr[k4];
        float hs[4] = {hv4.x, hv4.y, hv4.z, hv4.w};
        #pragma unroll
        for (int kk = 0; kk < 4; kk++) {
            float hv = hs[kk];
            int k = k4 * 4 + kk;
            #pragma unroll
            for (int c4 = 0; c4 < 10; c4++) {
                float4 w = Ws[k * 10 + c4];
                acc[c4 * 4 + 0] += hv * w.x;
                acc[c4 * 4 + 1] += hv * w.y;
                acc[c4 * 4 + 2] += hv * w.z;
                acc[c4 * 4 + 3] += hv * w.w;
            }
        }
    }
    float s1 = 0.f, s2 = 0.f;
    #pragma unroll
    for (int c = 0; c < 40; c++) { s1 += acc[c] * as2[c]; s2 += acc[c] * ad2[c]; }
    al2s[n] = s1;
    al2d[n] = s2;
    float4* h2r = (float4*)(h2 + (size_t)n * 40);
    #pragma unroll
    for (int c4 = 0; c4 < 10; c4++)
        h2r[c4] = make_float4(acc[c4 * 4], acc[c4 * 4 + 1], acc[c4 * 4 + 2], acc[c4 * 4 + 3]);
}

// ---------------- layer 2 aggregation + fused log_softmax -----------------------
__global__ __launch_bounds__(256) void k_agg2(
    const int* __restrict__ rowstart, const int* __restrict__ srcs,
    const float* __restrict__ al2s, const float* __restrict__ al2d,
    const float* __restrict__ h2, const float* __restrict__ b2,
    float* __restrict__ out) {
    int wave = threadIdx.x >> 6;
    int lane = threadIdx.x & 63;
    int d = blockIdx.x * 4 + wave;
    if (d >= NN) return;
    int c = lane;
    float adst = al2d[d];
    int jb = rowstart[d], je = rowstart[d + 1];
    float ssum = 0.f, acc = 0.f;
    bool act = (c < 40);
    int cc = act ? c : 0;
    int j = jb;
    for (; j + 4 <= je; j += 4) {
        int s0 = srcs[j], s1 = srcs[j + 1], s2 = srcs[j + 2], s3 = srcs[j + 3];
        float e0 = al2s[s0] + adst;
        float e1 = al2s[s1] + adst;
        float e2 = al2s[s2] + adst;
        float e3 = al2s[s3] + adst;
        float p0 = __expf(fmaxf(e0, 0.2f * e0));
        float p1 = __expf(fmaxf(e1, 0.2f * e1));
        float p2 = __expf(fmaxf(e2, 0.2f * e2));
        float p3 = __expf(fmaxf(e3, 0.2f * e3));
        float v0 = h2[(size_t)s0 * 40 + cc];
        float v1 = h2[(size_t)s1 * 40 + cc];
        float v2 = h2[(size_t)s2 * 40 + cc];
        float v3 = h2[(size_t)s3 * 40 + cc];
        ssum += (p0 + p1) + (p2 + p3);
        acc += p0 * v0 + p1 * v1 + p2 * v2 + p3 * v3;
    }
    for (; j < je; j++) {
        int s = srcs[j];
        float ea = al2s[s] + adst;
        float p = __expf(fmaxf(ea, 0.2f * ea));
        ssum += p;
        acc += p * h2[(size_t)s * 40 + cc];
    }
    float o = act ? (acc / ssum + b2[c]) : -3.0e38f;
    float m = o;
    #pragma unroll
    for (int off = 32; off; off >>= 1) m = fmaxf(m, __shfl_xor(m, off, 64));
    float t = act ? __expf(o - m) : 0.f;
    float sum = t;
    #pragma unroll
    for (int off = 32; off; off >>= 1) sum += __shfl_xor(sum, off, 64);
    if (act) out[(size_t)d * 40 + c] = o - m - __logf(sum);
}

extern "C" void kernel_launch(void* const* d_in, const int* in_sizes, int n_in,
                              void* d_out, int out_size, void* d_ws, size_t ws_size,
                              hipStream_t stream) {
    (void)in_sizes; (void)n_in; (void)out_size; (void)ws_size;
    const float* x    = (const float*)d_in[0];
    const float* topo = (const float*)d_in[1];
    const int*   ei   = (const int*)d_in[2];
    const float* W1   = (const float*)d_in[3];
    const float* as1  = (const float*)d_in[4];
    const float* ad1  = (const float*)d_in[5];
    const float* b1   = (const float*)d_in[6];
    const float* W2   = (const float*)d_in[7];
    const float* as2  = (const float*)d_in[8];
    const float* ad2  = (const float*)d_in[9];
    const float* b2   = (const float*)d_in[10];
    float* out = (float*)d_out;

    char* ws = (char*)d_ws;
    size_t off = 0;
    auto alloc = [&](size_t bytes) {
        void* p = ws + off;
        off += (bytes + 255) / 256 * 256;
        return p;
    };
    int* rowstart  = (int*)alloc((NN + 1) * 4);
    int* cnt       = (int*)alloc(NN * 4);        // doubles as scatter cursor
    int* blocksum  = (int*)alloc(256 * 4);
    int* srcs      = (int*)alloc(ET * 4);
    float* alsrc1  = (float*)alloc((size_t)NN * 8 * 4);
    float* aldst1  = (float*)alloc((size_t)NN * 8 * 4);
    float* al2s    = (float*)alloc(NN * 4);
    float* al2d    = (float*)alloc(NN * 4);
    float* h1      = (float*)alloc((size_t)NN * 64 * 4);
    float* hout    = (float*)alloc((size_t)NN * 64 * 4);
    float* h2      = h1;   // alias: h1 dead after k_agg1

    int egrid = (EE + 255) / 256;
    k_initcnt <<<NB,    256, 0, stream>>>(cnt);
    k_hist    <<<egrid, 256, 0, stream>>>(ei, cnt);
    k_scan1   <<<NB,    256, 0, stream>>>(cnt, rowstart, blocksum);
    k_scan2   <<<1,     256, 0, stream>>>(blocksum);
    k_finalize<<<NB1,   256, 0, stream>>>(rowstart, blocksum, cnt, srcs);
    k_scatter <<<egrid, 256, 0, stream>>>(ei, cnt, srcs);
    k_gemm1   <<<NB,    256, 0, stream>>>(x, topo, W1, as1, ad1, h1, alsrc1, aldst1);
    k_agg1    <<<(NN + 3) / 4, 256, 0, stream>>>(rowstart, srcs, alsrc1, aldst1, h1, b1, hout);
    k_gemm2   <<<NB,    256, 0, stream>>>(hout, W2, as2, ad2, h2, al2s, al2d);
    k_agg2    <<<(NN + 3) / 4, 256, 0, stream>>>(rowstart, srcs, al2s, al2d, h2, b2, out);
}

// Round 3
// 253.000 us; speedup vs baseline: 1.7534x; 1.2752x over previous
//
#include <hip/hip_runtime.h>

#define NN 50000
#define EE 800000
#define ET 850000   // EE + NN self loops
#define NB 196      // ceil(NN/256)
#define NBUCK 196   // dst buckets of 256 nodes each
#define CAP 5120    // per-bucket edge capacity (mean 4096, sigma ~64 -> 16 sigma)
#define TILEA 2048
#define NBA ((EE + TILEA - 1) / TILEA)   // 391

__global__ void k_zero(int* __restrict__ c) {
    int i = threadIdx.x;
    if (i < NBUCK) c[i] = 0;
}

// ---------- Pass A: coarse bucket by dst>>8, LDS-staged, coalesced-run writes ----
__global__ __launch_bounds__(256) void k_bucketA(const int* __restrict__ ei,
        int* __restrict__ cursor, unsigned* __restrict__ bucketData) {
    __shared__ int cnt[NBUCK], base[NBUCK];
    int t = threadIdx.x;
    for (int i = t; i < NBUCK; i += 256) cnt[i] = 0;
    __syncthreads();
    int e0 = blockIdx.x * TILEA;
    int nE = min(TILEA, EE - e0);
    unsigned pk[8]; int bk[8], rk[8];
    int m = 0;
    for (int i = t; i < nE; i += 256) {
        int e = e0 + i;
        int s = ei[e], d = ei[EE + e];
        pk[m] = ((unsigned)d << 16) | (unsigned)s;
        bk[m] = d >> 8;
        rk[m] = atomicAdd(&cnt[bk[m]], 1);
        m++;
    }
    __syncthreads();
    for (int i = t; i < NBUCK; i += 256)
        base[i] = (cnt[i] > 0) ? atomicAdd(&cursor[i], cnt[i]) : 0;
    __syncthreads();
    for (int k = 0; k < m; k++) {
        int pos = base[bk[k]] + rk[k];
        if (pos < CAP) bucketData[(size_t)bk[k] * CAP + pos] = pk[k];
    }
}

// ---------- scan bucket totals (incl self loops) -> bucketOut; rowstart[NN] -----
__global__ void k_scanB(const int* __restrict__ cursor, int* __restrict__ bucketOut,
                        int* __restrict__ rowstart) {
    __shared__ int s0[256], s1[256];
    int t = threadIdx.x;
    int nloc = (t < NBUCK) ? min(256, NN - t * 256) : 0;
    int v = (t < NBUCK) ? (min(cursor[t], CAP) + nloc) : 0;
    s0[t] = v;
    __syncthreads();
    int* a = s0; int* b = s1;
    for (int off = 1; off < 256; off <<= 1) {
        int x = a[t] + ((t >= off) ? a[t - off] : 0);
        b[t] = x;
        __syncthreads();
        int* tmp = a; a = b; b = tmp;
    }
    if (t < NBUCK) bucketOut[t] = a[t] - v;     // exclusive
    if (t == NBUCK - 1) rowstart[NN] = a[t];
}

// ---------- Pass B: per-bucket exact counting sort in LDS, coalesced output -----
__global__ __launch_bounds__(256) void k_bucketB(const unsigned* __restrict__ bucketData,
        const int* __restrict__ cursor, const int* __restrict__ bucketOut,
        int* __restrict__ rowstart, int* __restrict__ srcs) {
    __shared__ int cnt[256], cur[256], sbuf[256];
    __shared__ int sorted[CAP + 256];
    int b = blockIdx.x, t = threadIdx.x;
    int nloc = min(256, NN - b * 256);
    int ecnt = min(cursor[b], CAP);
    size_t inBase = (size_t)b * CAP;
    int outBase = bucketOut[b];
    cnt[t] = (t < nloc) ? 1 : 0;                 // +1 = self loop
    __syncthreads();
    for (int i = t; i < ecnt; i += 256) {
        unsigned u = bucketData[inBase + i];
        atomicAdd(&cnt[(u >> 16) & 255], 1);
    }
    __syncthreads();
    int cv = cnt[t];
    sbuf[t] = cv;
    __syncthreads();
    int* a = sbuf; int* bb = cnt;
    for (int off = 1; off < 256; off <<= 1) {
        int x = a[t] + ((t >= off) ? a[t - off] : 0);
        bb[t] = x;
        __syncthreads();
        int* tmp = a; a = bb; bb = tmp;
    }
    int excl = a[t] - cv;
    __syncthreads();
    if (t < nloc) {
        rowstart[b * 256 + t] = outBase + excl;
        sorted[excl] = b * 256 + t;              // self loop at slot 0 of segment
        cur[t] = excl + 1;
    } else {
        cur[t] = 0;
    }
    __syncthreads();
    for (int i = t; i < ecnt; i += 256) {
        unsigned u = bucketData[inBase + i];
        int ld = (u >> 16) & 255;
        int p = atomicAdd(&cur[ld], 1);
        sorted[p] = (int)(u & 0xffffu);
    }
    __syncthreads();
    int total = ecnt + nloc;
    for (int i = t; i < total; i += 256) srcs[outBase + i] = sorted[i];
}

// ---------------- layer 1 node GEMM: h1 = [x|topo] @ W1, plus attention logits ----
__global__ __launch_bounds__(256) void k_gemm1(
    const float* __restrict__ x, const float* __restrict__ topo,
    const float* __restrict__ W1, const float* __restrict__ a_src,
    const float* __restrict__ a_dst,
    float* __restrict__ h1, float* __restrict__ alsrc, float* __restrict__ aldst) {
    __shared__ float4 Ws[128 * 16];   // 128 x 64 floats
    for (int i = threadIdx.x; i < 2048; i += 256) Ws[i] = ((const float4*)W1)[i];
    __syncthreads();
    int n = blockIdx.x * 256 + threadIdx.x;
    if (n >= NN) return;
    float acc[64];
    #pragma unroll
    for (int c = 0; c < 64; c++) acc[c] = 0.f;
    const float4* xr = (const float4*)(x + (size_t)n * 120);
    const float4* tr = (const float4*)(topo + (size_t)n * 8);
    for (int k4 = 0; k4 < 32; k4++) {
        float4 xv4 = (k4 < 30) ? xr[k4] : tr[k4 - 30];
        float xs[4] = {xv4.x, xv4.y, xv4.z, xv4.w};
        #pragma unroll
        for (int kk = 0; kk < 4; kk++) {
            float xv = xs[kk];
            int k = k4 * 4 + kk;
            #pragma unroll
            for (int c4 = 0; c4 < 16; c4++) {
                float4 w = Ws[k * 16 + c4];
                acc[c4 * 4 + 0] += xv * w.x;
                acc[c4 * 4 + 1] += xv * w.y;
                acc[c4 * 4 + 2] += xv * w.z;
                acc[c4 * 4 + 3] += xv * w.w;
            }
        }
    }
    float4* hr = (float4*)(h1 + (size_t)n * 64);
    #pragma unroll
    for (int c4 = 0; c4 < 16; c4++)
        hr[c4] = make_float4(acc[c4 * 4], acc[c4 * 4 + 1], acc[c4 * 4 + 2], acc[c4 * 4 + 3]);
    #pragma unroll
    for (int h = 0; h < 8; h++) {
        float s1 = 0.f, s2 = 0.f;
        #pragma unroll
        for (int dd = 0; dd < 8; dd++) {
            float hv = acc[h * 8 + dd];
            s1 += hv * a_src[h * 8 + dd];
            s2 += hv * a_dst[h * 8 + dd];
        }
        alsrc[n * 8 + h] = s1;
        aldst[n * 8 + h] = s2;
    }
}

// ---------------- layer 1 aggregation: one wave per destination node -------------
__global__ __launch_bounds__(256) void k_agg1(
    const int* __restrict__ rowstart, const int* __restrict__ srcs,
    const float* __restrict__ alsrc, const float* __restrict__ aldst,
    const float* __restrict__ h1, const float* __restrict__ b1,
    float* __restrict__ hout) {
    int wave = threadIdx.x >> 6;
    int lane = threadIdx.x & 63;
    int d = blockIdx.x * 4 + wave;
    if (d >= NN) return;
    int c = lane;
    int h = lane >> 3;
    float adst = aldst[d * 8 + h];
    int jb = rowstart[d], je = rowstart[d + 1];
    float ssum = 0.f, acc = 0.f;
    int j = jb;
    for (; j + 4 <= je; j += 4) {
        int s0 = srcs[j], s1 = srcs[j + 1], s2 = srcs[j + 2], s3 = srcs[j + 3];
        float e0 = alsrc[s0 * 8 + h] + adst;
        float e1 = alsrc[s1 * 8 + h] + adst;
        float e2 = alsrc[s2 * 8 + h] + adst;
        float e3 = alsrc[s3 * 8 + h] + adst;
        float p0 = __expf(fmaxf(e0, 0.2f * e0));
        float p1 = __expf(fmaxf(e1, 0.2f * e1));
        float p2 = __expf(fmaxf(e2, 0.2f * e2));
        float p3 = __expf(fmaxf(e3, 0.2f * e3));
        float v0 = h1[(size_t)s0 * 64 + c];
        float v1 = h1[(size_t)s1 * 64 + c];
        float v2 = h1[(size_t)s2 * 64 + c];
        float v3 = h1[(size_t)s3 * 64 + c];
        ssum += (p0 + p1) + (p2 + p3);
        acc += p0 * v0 + p1 * v1 + p2 * v2 + p3 * v3;
    }
    for (; j < je; j++) {
        int s = srcs[j];
        float ea = alsrc[s * 8 + h] + adst;
        float p = __expf(fmaxf(ea, 0.2f * ea));
        ssum += p;
        acc += p * h1[(size_t)s * 64 + c];
    }
    float val = acc / ssum + b1[c];
    val = (val > 0.f) ? val : (__expf(val) - 1.f);   // ELU
    hout[(size_t)d * 64 + c] = val;
}

// ---------------- layer 2 node GEMM ---------------------------------------------
__global__ __launch_bounds__(256) void k_gemm2(
    const float* __restrict__ hout, const float* __restrict__ W2,
    const float* __restrict__ a_src2, const float* __restrict__ a_dst2,
    float* __restrict__ h2, float* __restrict__ al2s, float* __restrict__ al2d) {
    __shared__ float4 Ws[640];        // 64 x 40 floats
    __shared__ float as2[40], ad2[40];
    for (int i = threadIdx.x; i < 640; i += 256) Ws[i] = ((const float4*)W2)[i];
    if (threadIdx.x < 40) {
        as2[threadIdx.x] = a_src2[threadIdx.x];
        ad2[threadIdx.x] = a_dst2[threadIdx.x];
    }
    __syncthreads();
    int n = blockIdx.x * 256 + threadIdx.x;
    if (n >= NN) return;
    float acc[40];
    #pragma unroll
    for (int c = 0; c < 40; c++) acc[c] = 0.f;
    const float4* hr = (const float4*)(hout + (size_t)n * 64);
    for (int k4 = 0; k4 < 16; k4++) {
        float4 hv4 = hr[k4];
        float hs[4] = {hv4.x, hv4.y, hv4.z, hv4.w};
        #pragma unroll
        for (int kk = 0; kk < 4; kk++) {
            float hv = hs[kk];
            int k = k4 * 4 + kk;
            #pragma unroll
            for (int c4 = 0; c4 < 10; c4++) {
                float4 w = Ws[k * 10 + c4];
                acc[c4 * 4 + 0] += hv * w.x;
                acc[c4 * 4 + 1] += hv * w.y;
                acc[c4 * 4 + 2] += hv * w.z;
                acc[c4 * 4 + 3] += hv * w.w;
            }
        }
    }
    float s1 = 0.f, s2 = 0.f;
    #pragma unroll
    for (int c = 0; c < 40; c++) { s1 += acc[c] * as2[c]; s2 += acc[c] * ad2[c]; }
    al2s[n] = s1;
    al2d[n] = s2;
    float4* h2r = (float4*)(h2 + (size_t)n * 40);
    #pragma unroll
    for (int c4 = 0; c4 < 10; c4++)
        h2r[c4] = make_float4(acc[c4 * 4], acc[c4 * 4 + 1], acc[c4 * 4 + 2], acc[c4 * 4 + 3]);
}

// ---------------- layer 2 aggregation + fused log_softmax -----------------------
__global__ __launch_bounds__(256) void k_agg2(
    const int* __restrict__ rowstart, const int* __restrict__ srcs,
    const float* __restrict__ al2s, const float* __restrict__ al2d,
    const float* __restrict__ h2, const float* __restrict__ b2,
    float* __restrict__ out) {
    int wave = threadIdx.x >> 6;
    int lane = threadIdx.x & 63;
    int d = blockIdx.x * 4 + wave;
    if (d >= NN) return;
    int c = lane;
    float adst = al2d[d];
    int jb = rowstart[d], je = rowstart[d + 1];
    float ssum = 0.f, acc = 0.f;
    bool act = (c < 40);
    int cc = act ? c : 0;
    int j = jb;
    for (; j + 4 <= je; j += 4) {
        int s0 = srcs[j], s1 = srcs[j + 1], s2 = srcs[j + 2], s3 = srcs[j + 3];
        float e0 = al2s[s0] + adst;
        float e1 = al2s[s1] + adst;
        float e2 = al2s[s2] + adst;
        float e3 = al2s[s3] + adst;
        float p0 = __expf(fmaxf(e0, 0.2f * e0));
        float p1 = __expf(fmaxf(e1, 0.2f * e1));
        float p2 = __expf(fmaxf(e2, 0.2f * e2));
        float p3 = __expf(fmaxf(e3, 0.2f * e3));
        float v0 = h2[(size_t)s0 * 40 + cc];
        float v1 = h2[(size_t)s1 * 40 + cc];
        float v2 = h2[(size_t)s2 * 40 + cc];
        float v3 = h2[(size_t)s3 * 40 + cc];
        ssum += (p0 + p1) + (p2 + p3);
        acc += p0 * v0 + p1 * v1 + p2 * v2 + p3 * v3;
    }
    for (; j < je; j++) {
        int s = srcs[j];
        float ea = al2s[s] + adst;
        float p = __expf(fmaxf(ea, 0.2f * ea));
        ssum += p;
        acc += p * h2[(size_t)s * 40 + cc];
    }
    float o = act ? (acc / ssum + b2[c]) : -3.0e38f;
    float m = o;
    #pragma unroll
    for (int off = 32; off; off >>= 1) m = fmaxf(m, __shfl_xor(m, off, 64));
    float t = act ? __expf(o - m) : 0.f;
    float sum = t;
    #pragma unroll
    for (int off = 32; off; off >>= 1) sum += __shfl_xor(sum, off, 64);
    if (act) out[(size_t)d * 40 + c] = o - m - __logf(sum);
}

extern "C" void kernel_launch(void* const* d_in, const int* in_sizes, int n_in,
                              void* d_out, int out_size, void* d_ws, size_t ws_size,
                              hipStream_t stream) {
    (void)in_sizes; (void)n_in; (void)out_size; (void)ws_size;
    const float* x    = (const float*)d_in[0];
    const float* topo = (const float*)d_in[1];
    const int*   ei   = (const int*)d_in[2];
    const float* W1   = (const float*)d_in[3];
    const float* as1  = (const float*)d_in[4];
    const float* ad1  = (const float*)d_in[5];
    const float* b1   = (const float*)d_in[6];
    const float* W2   = (const float*)d_in[7];
    const float* as2  = (const float*)d_in[8];
    const float* ad2  = (const float*)d_in[9];
    const float* b2   = (const float*)d_in[10];
    float* out = (float*)d_out;

    char* ws = (char*)d_ws;
    size_t off = 0;
    auto alloc = [&](size_t bytes) {
        void* p = ws + off;
        off += (bytes + 255) / 256 * 256;
        return p;
    };
    int*      rowstart   = (int*)alloc((NN + 1) * 4);
    int*      cursor     = (int*)alloc(NBUCK * 4);
    int*      bucketOut  = (int*)alloc(NBUCK * 4);
    unsigned* bucketData = (unsigned*)alloc((size_t)NBUCK * CAP * 4);
    int*      srcs       = (int*)alloc(ET * 4);
    float*    alsrc1     = (float*)alloc((size_t)NN * 8 * 4);
    float*    aldst1     = (float*)alloc((size_t)NN * 8 * 4);
    float*    al2s       = (float*)alloc(NN * 4);
    float*    al2d       = (float*)alloc(NN * 4);
    float*    h1         = (float*)alloc((size_t)NN * 64 * 4);
    float*    hout       = (float*)alloc((size_t)NN * 64 * 4);
    float*    h2         = h1;   // alias: h1 dead after k_agg1

    k_zero    <<<1,     256, 0, stream>>>(cursor);
    k_bucketA <<<NBA,   256, 0, stream>>>(ei, cursor, bucketData);
    k_scanB   <<<1,     256, 0, stream>>>(cursor, bucketOut, rowstart);
    k_bucketB <<<NBUCK, 256, 0, stream>>>(bucketData, cursor, bucketOut, rowstart, srcs);
    k_gemm1   <<<NB,    256, 0, stream>>>(x, topo, W1, as1, ad1, h1, alsrc1, aldst1);
    k_agg1    <<<(NN + 3) / 4, 256, 0, stream>>>(rowstart, srcs, alsrc1, aldst1, h1, b1, hout);
    k_gemm2   <<<NB,    256, 0, stream>>>(hout, W2, as2, ad2, h2, al2s, al2d);
    k_agg2    <<<(NN + 3) / 4, 256, 0, stream>>>(rowstart, srcs, al2s, al2d, h2, b2, out);
}

// Round 4
// 245.921 us; speedup vs baseline: 1.8039x; 1.0288x over previous
//
#include <hip/hip_runtime.h>
#include <hip/hip_fp16.h>

#define NN 50000
#define EE 800000
#define ET 850000   // EE + NN self loops
#define NB 196      // ceil(NN/256)
#define NBUCK 196   // dst buckets of 256 nodes each
#define CAP 5120    // per-bucket edge capacity (mean 4096, sigma ~64 -> 16 sigma)
#define TILEA 2048
#define NBA ((EE + TILEA - 1) / TILEA)   // 391

__device__ __forceinline__ unsigned packh2(float a, float b) {
    __half2 h = __floats2half2_rn(a, b);
    return *(unsigned*)&h;
}

__global__ void k_zero(int* __restrict__ c) {
    int i = threadIdx.x;
    if (i < NBUCK) c[i] = 0;
}

// ---------- Pass A: coarse bucket by dst>>8, LDS-staged, coalesced-run writes ----
__global__ __launch_bounds__(256) void k_bucketA(const int* __restrict__ ei,
        int* __restrict__ cursor, unsigned* __restrict__ bucketData) {
    __shared__ int cnt[NBUCK], base[NBUCK];
    int t = threadIdx.x;
    for (int i = t; i < NBUCK; i += 256) cnt[i] = 0;
    __syncthreads();
    int e0 = blockIdx.x * TILEA;
    int nE = min(TILEA, EE - e0);
    unsigned pk[8]; int bk[8], rk[8];
    int m = 0;
    for (int i = t; i < nE; i += 256) {
        int e = e0 + i;
        int s = ei[e], d = ei[EE + e];
        pk[m] = ((unsigned)d << 16) | (unsigned)s;
        bk[m] = d >> 8;
        rk[m] = atomicAdd(&cnt[bk[m]], 1);
        m++;
    }
    __syncthreads();
    for (int i = t; i < NBUCK; i += 256)
        base[i] = (cnt[i] > 0) ? atomicAdd(&cursor[i], cnt[i]) : 0;
    __syncthreads();
    for (int k = 0; k < m; k++) {
        int pos = base[bk[k]] + rk[k];
        if (pos < CAP) bucketData[(size_t)bk[k] * CAP + pos] = pk[k];
    }
}

// ---------- scan bucket totals (incl self loops) -> bucketOut; rowstart[NN] -----
__global__ void k_scanB(const int* __restrict__ cursor, int* __restrict__ bucketOut,
                        int* __restrict__ rowstart) {
    __shared__ int s0[256], s1[256];
    int t = threadIdx.x;
    int nloc = (t < NBUCK) ? min(256, NN - t * 256) : 0;
    int v = (t < NBUCK) ? (min(cursor[t], CAP) + nloc) : 0;
    s0[t] = v;
    __syncthreads();
    int* a = s0; int* b = s1;
    for (int off = 1; off < 256; off <<= 1) {
        int x = a[t] + ((t >= off) ? a[t - off] : 0);
        b[t] = x;
        __syncthreads();
        int* tmp = a; a = b; b = tmp;
    }
    if (t < NBUCK) bucketOut[t] = a[t] - v;     // exclusive
    if (t == NBUCK - 1) rowstart[NN] = a[t];
}

// ---------- Pass B: per-bucket exact counting sort in LDS, coalesced output -----
__global__ __launch_bounds__(256) void k_bucketB(const unsigned* __restrict__ bucketData,
        const int* __restrict__ cursor, const int* __restrict__ bucketOut,
        int* __restrict__ rowstart, int* __restrict__ srcs) {
    __shared__ int cnt[256], cur[256], sbuf[256];
    __shared__ int sorted[CAP + 256];
    int b = blockIdx.x, t = threadIdx.x;
    int nloc = min(256, NN - b * 256);
    int ecnt = min(cursor[b], CAP);
    size_t inBase = (size_t)b * CAP;
    int outBase = bucketOut[b];
    cnt[t] = (t < nloc) ? 1 : 0;                 // +1 = self loop
    __syncthreads();
    for (int i = t; i < ecnt; i += 256) {
        unsigned u = bucketData[inBase + i];
        atomicAdd(&cnt[(u >> 16) & 255], 1);
    }
    __syncthreads();
    int cv = cnt[t];
    sbuf[t] = cv;
    __syncthreads();
    int* a = sbuf; int* bb = cnt;
    for (int off = 1; off < 256; off <<= 1) {
        int x = a[t] + ((t >= off) ? a[t - off] : 0);
        bb[t] = x;
        __syncthreads();
        int* tmp = a; a = bb; bb = tmp;
    }
    int excl = a[t] - cv;
    __syncthreads();
    if (t < nloc) {
        rowstart[b * 256 + t] = outBase + excl;
        sorted[excl] = b * 256 + t;              // self loop at slot 0 of segment
        cur[t] = excl + 1;
    } else {
        cur[t] = 0;
    }
    __syncthreads();
    for (int i = t; i < ecnt; i += 256) {
        unsigned u = bucketData[inBase + i];
        int ld = (u >> 16) & 255;
        int p = atomicAdd(&cur[ld], 1);
        sorted[p] = (int)(u & 0xffffu);
    }
    __syncthreads();
    int total = ecnt + nloc;
    for (int i = t; i < total; i += 256) srcs[outBase + i] = sorted[i];
}

// ---------------- layer 1 node GEMM: h1(fp16) = [x|topo] @ W1, + attention logits
__global__ __launch_bounds__(256) void k_gemm1(
    const float* __restrict__ x, const float* __restrict__ topo,
    const float* __restrict__ W1, const float* __restrict__ a_src,
    const float* __restrict__ a_dst,
    __half* __restrict__ h1, float* __restrict__ alsrc, float* __restrict__ aldst) {
    __shared__ float4 Ws[128 * 16];   // 128 x 64 floats
    for (int i = threadIdx.x; i < 2048; i += 256) Ws[i] = ((const float4*)W1)[i];
    __syncthreads();
    int n = blockIdx.x * 256 + threadIdx.x;
    if (n >= NN) return;
    float acc[64];
    #pragma unroll
    for (int c = 0; c < 64; c++) acc[c] = 0.f;
    const float4* xr = (const float4*)(x + (size_t)n * 120);
    const float4* tr = (const float4*)(topo + (size_t)n * 8);
    for (int k4 = 0; k4 < 32; k4++) {
        float4 xv4 = (k4 < 30) ? xr[k4] : tr[k4 - 30];
        float xs[4] = {xv4.x, xv4.y, xv4.z, xv4.w};
        #pragma unroll
        for (int kk = 0; kk < 4; kk++) {
            float xv = xs[kk];
            int k = k4 * 4 + kk;
            #pragma unroll
            for (int c4 = 0; c4 < 16; c4++) {
                float4 w = Ws[k * 16 + c4];
                acc[c4 * 4 + 0] += xv * w.x;
                acc[c4 * 4 + 1] += xv * w.y;
                acc[c4 * 4 + 2] += xv * w.z;
                acc[c4 * 4 + 3] += xv * w.w;
            }
        }
    }
    unsigned up[32];
    #pragma unroll
    for (int i = 0; i < 32; i++) up[i] = packh2(acc[2 * i], acc[2 * i + 1]);
    uint4* hr = (uint4*)(h1 + (size_t)n * 64);
    #pragma unroll
    for (int i = 0; i < 8; i++)
        hr[i] = make_uint4(up[4 * i], up[4 * i + 1], up[4 * i + 2], up[4 * i + 3]);
    #pragma unroll
    for (int h = 0; h < 8; h++) {
        float s1 = 0.f, s2 = 0.f;
        #pragma unroll
        for (int dd = 0; dd < 8; dd++) {
            float hv = acc[h * 8 + dd];
            s1 += hv * a_src[h * 8 + dd];
            s2 += hv * a_dst[h * 8 + dd];
        }
        alsrc[n * 8 + h] = s1;
        aldst[n * 8 + h] = s2;
    }
}

// ------- layer 1 aggregation: wave/dst, 2 edges per iter (lane halves), fp16 vals
__global__ __launch_bounds__(256) void k_agg1(
    const int* __restrict__ rowstart, const int* __restrict__ srcs,
    const float* __restrict__ alsrc, const float* __restrict__ aldst,
    const __half* __restrict__ h1, const float* __restrict__ b1,
    float* __restrict__ hout) {
    int wave = threadIdx.x >> 6;
    int lane = threadIdx.x & 63;
    int d = blockIdx.x * 4 + wave;
    if (d >= NN) return;
    int half = lane >> 5;        // which edge of the pair
    int cp = lane & 31;          // col pair: cols 2cp, 2cp+1
    int h = cp >> 2;             // head = (2cp)>>3
    float adst = aldst[d * 8 + h];
    int jb = rowstart[d], je = rowstart[d + 1];
    float ssum = 0.f;
    float ax = 0.f, ay = 0.f;
    int j = jb;
    for (; j + 8 <= je; j += 8) {
        int s0 = srcs[j + half], s1 = srcs[j + 2 + half];
        int s2 = srcs[j + 4 + half], s3 = srcs[j + 6 + half];
        float e0 = alsrc[s0 * 8 + h] + adst;
        float e1 = alsrc[s1 * 8 + h] + adst;
        float e2 = alsrc[s2 * 8 + h] + adst;
        float e3 = alsrc[s3 * 8 + h] + adst;
        __half2 v0 = *(const __half2*)(h1 + (size_t)s0 * 64 + 2 * cp);
        __half2 v1 = *(const __half2*)(h1 + (size_t)s1 * 64 + 2 * cp);
        __half2 v2 = *(const __half2*)(h1 + (size_t)s2 * 64 + 2 * cp);
        __half2 v3 = *(const __half2*)(h1 + (size_t)s3 * 64 + 2 * cp);
        float p0 = __expf(fmaxf(e0, 0.2f * e0));
        float p1 = __expf(fmaxf(e1, 0.2f * e1));
        float p2 = __expf(fmaxf(e2, 0.2f * e2));
        float p3 = __expf(fmaxf(e3, 0.2f * e3));
        float2 f0 = __half22float2(v0), f1 = __half22float2(v1);
        float2 f2 = __half22float2(v2), f3 = __half22float2(v3);
        ssum += (p0 + p1) + (p2 + p3);
        ax += p0 * f0.x + p1 * f1.x + p2 * f2.x + p3 * f3.x;
        ay += p0 * f0.y + p1 * f1.y + p2 * f2.y + p3 * f3.y;
    }
    for (; j < je; j += 2) {
        int e = j + half;
        bool valid = (e < je);
        int s = srcs[valid ? e : jb];
        float ea = alsrc[s * 8 + h] + adst;
        float p = valid ? __expf(fmaxf(ea, 0.2f * ea)) : 0.f;
        float2 f = __half22float2(*(const __half2*)(h1 + (size_t)s * 64 + 2 * cp));
        ssum += p;
        ax += p * f.x;
        ay += p * f.y;
    }
    ssum += __shfl_xor(ssum, 32, 64);
    ax += __shfl_xor(ax, 32, 64);
    ay += __shfl_xor(ay, 32, 64);
    if (half == 0) {
        float2 bv = *(const float2*)(b1 + 2 * cp);
        float inv = 1.f / ssum;
        float vx = ax * inv + bv.x;
        float vy = ay * inv + bv.y;
        vx = (vx > 0.f) ? vx : (__expf(vx) - 1.f);   // ELU
        vy = (vy > 0.f) ? vy : (__expf(vy) - 1.f);
        *(float2*)(hout + (size_t)d * 64 + 2 * cp) = make_float2(vx, vy);
    }
}

// ---------------- layer 2 node GEMM (h2 fp16) ------------------------------------
__global__ __launch_bounds__(256) void k_gemm2(
    const float* __restrict__ hout, const float* __restrict__ W2,
    const float* __restrict__ a_src2, const float* __restrict__ a_dst2,
    __half* __restrict__ h2, float* __restrict__ al2s, float* __restrict__ al2d) {
    __shared__ float4 Ws[640];        // 64 x 40 floats
    __shared__ float as2[40], ad2[40];
    for (int i = threadIdx.x; i < 640; i += 256) Ws[i] = ((const float4*)W2)[i];
    if (threadIdx.x < 40) {
        as2[threadIdx.x] = a_src2[threadIdx.x];
        ad2[threadIdx.x] = a_dst2[threadIdx.x];
    }
    __syncthreads();
    int n = blockIdx.x * 256 + threadIdx.x;
    if (n >= NN) return;
    float acc[40];
    #pragma unroll
    for (int c = 0; c < 40; c++) acc[c] = 0.f;
    const float4* hr = (const float4*)(hout + (size_t)n * 64);
    for (int k4 = 0; k4 < 16; k4++) {
        float4 hv4 = hr[k4];
        float hs[4] = {hv4.x, hv4.y, hv4.z, hv4.w};
        #pragma unroll
        for (int kk = 0; kk < 4; kk++) {
            float hv = hs[kk];
            int k = k4 * 4 + kk;
            #pragma unroll
            for (int c4 = 0; c4 < 10; c4++) {
                float4 w = Ws[k * 10 + c4];
                acc[c4 * 4 + 0] += hv * w.x;
                acc[c4 * 4 + 1] += hv * w.y;
                acc[c4 * 4 + 2] += hv * w.z;
                acc[c4 * 4 + 3] += hv * w.w;
            }
        }
    }
    float s1 = 0.f, s2 = 0.f;
    #pragma unroll
    for (int c = 0; c < 40; c++) { s1 += acc[c] * as2[c]; s2 += acc[c] * ad2[c]; }
    al2s[n] = s1;
    al2d[n] = s2;
    unsigned up[20];
    #pragma unroll
    for (int i = 0; i < 20; i++) up[i] = packh2(acc[2 * i], acc[2 * i + 1]);
    uint4* h2r = (uint4*)(h2 + (size_t)n * 40);
    #pragma unroll
    for (int i = 0; i < 5; i++)
        h2r[i] = make_uint4(up[4 * i], up[4 * i + 1], up[4 * i + 2], up[4 * i + 3]);
}

// ------- layer 2 aggregation + fused log_softmax, 2 edges/iter, fp16 vals -------
__global__ __launch_bounds__(256) void k_agg2(
    const int* __restrict__ rowstart, const int* __restrict__ srcs,
    const float* __restrict__ al2s, const float* __restrict__ al2d,
    const __half* __restrict__ h2, const float* __restrict__ b2,
    float* __restrict__ out) {
    int wave = threadIdx.x >> 6;
    int lane = threadIdx.x & 63;
    int d = blockIdx.x * 4 + wave;
    if (d >= NN) return;
    int half = lane >> 5;
    int cp = lane & 31;              // cols 2cp,2cp+1; valid if cp<20
    bool act = (cp < 20);
    int cpc = act ? cp : 0;
    float adst = al2d[d];
    int jb = rowstart[d], je = rowstart[d + 1];
    float ssum = 0.f, ax = 0.f, ay = 0.f;
    int j = jb;
    for (; j + 8 <= je; j += 8) {
        int s0 = srcs[j + half], s1 = srcs[j + 2 + half];
        int s2 = srcs[j + 4 + half], s3 = srcs[j + 6 + half];
        float e0 = al2s[s0] + adst;
        float e1 = al2s[s1] + adst;
        float e2 = al2s[s2] + adst;
        float e3 = al2s[s3] + adst;
        __half2 v0 = *(const __half2*)(h2 + (size_t)s0 * 40 + 2 * cpc);
        __half2 v1 = *(const __half2*)(h2 + (size_t)s1 * 40 + 2 * cpc);
        __half2 v2 = *(const __half2*)(h2 + (size_t)s2 * 40 + 2 * cpc);
        __half2 v3 = *(const __half2*)(h2 + (size_t)s3 * 40 + 2 * cpc);
        float p0 = __expf(fmaxf(e0, 0.2f * e0));
        float p1 = __expf(fmaxf(e1, 0.2f * e1));
        float p2 = __expf(fmaxf(e2, 0.2f * e2));
        float p3 = __expf(fmaxf(e3, 0.2f * e3));
        float2 f0 = __half22float2(v0), f1 = __half22float2(v1);
        float2 f2 = __half22float2(v2), f3 = __half22float2(v3);
        ssum += (p0 + p1) + (p2 + p3);
        ax += p0 * f0.x + p1 * f1.x + p2 * f2.x + p3 * f3.x;
        ay += p0 * f0.y + p1 * f1.y + p2 * f2.y + p3 * f3.y;
    }
    for (; j < je; j += 2) {
        int e = j + half;
        bool valid = (e < je);
        int s = srcs[valid ? e : jb];
        float ea = al2s[s] + adst;
        float p = valid ? __expf(fmaxf(ea, 0.2f * ea)) : 0.f;
        float2 f = __half22float2(*(const __half2*)(h2 + (size_t)s * 40 + 2 * cpc));
        ssum += p;
        ax += p * f.x;
        ay += p * f.y;
    }
    ssum += __shfl_xor(ssum, 32, 64);
    ax += __shfl_xor(ax, 32, 64);
    ay += __shfl_xor(ay, 32, 64);
    // all lanes now hold totals for col pair cp; log-softmax within each 32-lane half
    float inv = 1.f / ssum;
    float2 bv = *(const float2*)(b2 + 2 * cpc);
    float ox = ax * inv + bv.x;
    float oy = ay * inv + bv.y;
    float mo = act ? fmaxf(ox, oy) : -3.0e38f;
    #pragma unroll
    for (int off = 16; off; off >>= 1) mo = fmaxf(mo, __shfl_xor(mo, off, 64));
    float te = act ? (__expf(ox - mo) + __expf(oy - mo)) : 0.f;
    #pragma unroll
    for (int off = 16; off; off >>= 1) te += __shfl_xor(te, off, 64);
    float ls = __logf(te);
    if (act && half == 0)
        *(float2*)(out + (size_t)d * 40 + 2 * cp) = make_float2(ox - mo - ls, oy - mo - ls);
}

extern "C" void kernel_launch(void* const* d_in, const int* in_sizes, int n_in,
                              void* d_out, int out_size, void* d_ws, size_t ws_size,
                              hipStream_t stream) {
    (void)in_sizes; (void)n_in; (void)out_size; (void)ws_size;
    const float* x    = (const float*)d_in[0];
    const float* topo = (const float*)d_in[1];
    const int*   ei   = (const int*)d_in[2];
    const float* W1   = (const float*)d_in[3];
    const float* as1  = (const float*)d_in[4];
    const float* ad1  = (const float*)d_in[5];
    const float* b1   = (const float*)d_in[6];
    const float* W2   = (const float*)d_in[7];
    const float* as2  = (const float*)d_in[8];
    const float* ad2  = (const float*)d_in[9];
    const float* b2   = (const float*)d_in[10];
    float* out = (float*)d_out;

    char* ws = (char*)d_ws;
    size_t off = 0;
    auto alloc = [&](size_t bytes) {
        void* p = ws + off;
        off += (bytes + 255) / 256 * 256;
        return p;
    };
    int*      rowstart   = (int*)alloc((NN + 1) * 4);
    int*      cursor     = (int*)alloc(NBUCK * 4);
    int*      bucketOut  = (int*)alloc(NBUCK * 4);
    unsigned* bucketData = (unsigned*)alloc((size_t)NBUCK * CAP * 4);
    int*      srcs       = (int*)alloc(ET * 4);
    float*    alsrc1     = (float*)alloc((size_t)NN * 8 * 4);
    float*    aldst1     = (float*)alloc((size_t)NN * 8 * 4);
    float*    al2s       = (float*)alloc(NN * 4);
    float*    al2d       = (float*)alloc(NN * 4);
    __half*   h1         = (__half*)alloc((size_t)NN * 64 * 2);
    float*    hout       = (float*)alloc((size_t)NN * 64 * 4);
    __half*   h2         = h1;   // alias: h1 dead after k_agg1 (4 MB <= 6.4 MB)

    k_zero    <<<1,     256, 0, stream>>>(cursor);
    k_bucketA <<<NBA,   256, 0, stream>>>(ei, cursor, bucketData);
    k_scanB   <<<1,     256, 0, stream>>>(cursor, bucketOut, rowstart);
    k_bucketB <<<NBUCK, 256, 0, stream>>>(bucketData, cursor, bucketOut, rowstart, srcs);
    k_gemm1   <<<NB,    256, 0, stream>>>(x, topo, W1, as1, ad1, h1, alsrc1, aldst1);
    k_agg1    <<<(NN + 3) / 4, 256, 0, stream>>>(rowstart, srcs, alsrc1, aldst1, h1, b1, hout);
    k_gemm2   <<<NB,    256, 0, stream>>>(hout, W2, as2, ad2, h2, al2s, al2d);
    k_agg2    <<<(NN + 3) / 4, 256, 0, stream>>>(rowstart, srcs, al2s, al2d, h2, b2, out);
}

// Round 5
// 204.333 us; speedup vs baseline: 2.1710x; 1.2035x over previous
//
#include <hip/hip_runtime.h>
#include <hip/hip_fp16.h>

#define NN 50000
#define EE 800000
#define ET 850000   // EE + NN self loops
#define NBUCK 196   // dst buckets of 256 nodes each
#define CAP 5120    // per-bucket edge capacity (mean 4096, sigma ~64 -> 16 sigma)
#define TILEA 2048
#define NBA ((EE + TILEA - 1) / TILEA)   // 391
#define NGB 782     // ceil(50000/64) row blocks for MFMA gemms

typedef _Float16 half8 __attribute__((ext_vector_type(8)));
typedef float floatx4 __attribute__((ext_vector_type(4)));

__global__ void k_zero(int* __restrict__ c) {
    int i = threadIdx.x;
    if (i < NBUCK) c[i] = 0;
}

// ---------- Pass A: coarse bucket by dst>>8, LDS-staged, coalesced-run writes ----
__global__ __launch_bounds__(256) void k_bucketA(const int* __restrict__ ei,
        int* __restrict__ cursor, unsigned* __restrict__ bucketData) {
    __shared__ int cnt[NBUCK], base[NBUCK];
    int t = threadIdx.x;
    for (int i = t; i < NBUCK; i += 256) cnt[i] = 0;
    __syncthreads();
    int e0 = blockIdx.x * TILEA;
    int nE = min(TILEA, EE - e0);
    unsigned pk[8]; int bk[8], rk[8];
    int m = 0;
    for (int i = t; i < nE; i += 256) {
        int e = e0 + i;
        int s = ei[e], d = ei[EE + e];
        pk[m] = ((unsigned)d << 16) | (unsigned)s;
        bk[m] = d >> 8;
        rk[m] = atomicAdd(&cnt[bk[m]], 1);
        m++;
    }
    __syncthreads();
    for (int i = t; i < NBUCK; i += 256)
        base[i] = (cnt[i] > 0) ? atomicAdd(&cursor[i], cnt[i]) : 0;
    __syncthreads();
    for (int k = 0; k < m; k++) {
        int pos = base[bk[k]] + rk[k];
        if (pos < CAP) bucketData[(size_t)bk[k] * CAP + pos] = pk[k];
    }
}

// ---------- scan bucket totals (incl self loops) -> bucketOut; rowstart[NN] -----
__global__ void k_scanB(const int* __restrict__ cursor, int* __restrict__ bucketOut,
                        int* __restrict__ rowstart) {
    __shared__ int s0[256], s1[256];
    int t = threadIdx.x;
    int nloc = (t < NBUCK) ? min(256, NN - t * 256) : 0;
    int v = (t < NBUCK) ? (min(cursor[t], CAP) + nloc) : 0;
    s0[t] = v;
    __syncthreads();
    int* a = s0; int* b = s1;
    for (int off = 1; off < 256; off <<= 1) {
        int x = a[t] + ((t >= off) ? a[t - off] : 0);
        b[t] = x;
        __syncthreads();
        int* tmp = a; a = b; b = tmp;
    }
    if (t < NBUCK) bucketOut[t] = a[t] - v;     // exclusive
    if (t == NBUCK - 1) rowstart[NN] = a[t];
}

// ---------- Pass B: per-bucket exact counting sort in LDS, coalesced output -----
__global__ __launch_bounds__(256) void k_bucketB(const unsigned* __restrict__ bucketData,
        const int* __restrict__ cursor, const int* __restrict__ bucketOut,
        int* __restrict__ rowstart, int* __restrict__ srcs) {
    __shared__ int cnt[256], cur[256], sbuf[256];
    __shared__ int sorted[CAP + 256];
    int b = blockIdx.x, t = threadIdx.x;
    int nloc = min(256, NN - b * 256);
    int ecnt = min(cursor[b], CAP);
    size_t inBase = (size_t)b * CAP;
    int outBase = bucketOut[b];
    cnt[t] = (t < nloc) ? 1 : 0;                 // +1 = self loop
    __syncthreads();
    for (int i = t; i < ecnt; i += 256) {
        unsigned u = bucketData[inBase + i];
        atomicAdd(&cnt[(u >> 16) & 255], 1);
    }
    __syncthreads();
    int cv = cnt[t];
    sbuf[t] = cv;
    __syncthreads();
    int* a = sbuf; int* bb = cnt;
    for (int off = 1; off < 256; off <<= 1) {
        int x = a[t] + ((t >= off) ? a[t - off] : 0);
        bb[t] = x;
        __syncthreads();
        int* tmp = a; a = bb; bb = tmp;
    }
    int excl = a[t] - cv;
    __syncthreads();
    if (t < nloc) {
        rowstart[b * 256 + t] = outBase + excl;
        sorted[excl] = b * 256 + t;              // self loop at slot 0 of segment
        cur[t] = excl + 1;
    } else {
        cur[t] = 0;
    }
    __syncthreads();
    for (int i = t; i < ecnt; i += 256) {
        unsigned u = bucketData[inBase + i];
        int ld = (u >> 16) & 255;
        int p = atomicAdd(&cur[ld], 1);
        sorted[p] = (int)(u & 0xffffu);
    }
    __syncthreads();
    int total = ecnt + nloc;
    for (int i = t; i < total; i += 256) srcs[outBase + i] = sorted[i];
}

// ---------- prep: W1/W2 -> fp16 MFMA B-fragment layout --------------------------
// Bf1[kk(4)][ct(4)][lane(64)][8]: B[n=ct*16+(L&15)][k=kk*32+(L>>4)*8+j]
// Bf2[kk(2)][ct(3)][lane(64)][8]: cols >= 40 zero-padded
__global__ void k_prep(const float* __restrict__ W1, const float* __restrict__ W2,
                       _Float16* __restrict__ Bf1, _Float16* __restrict__ Bf2) {
    int tid = blockIdx.x * 256 + threadIdx.x;
    if (tid < 1024) {
        int kk = tid >> 8, ct = (tid >> 6) & 3, L = tid & 63;
        int k0 = kk * 32 + (L >> 4) * 8, col = ct * 16 + (L & 15);
        half8 v;
        #pragma unroll
        for (int j = 0; j < 8; j++) v[j] = (_Float16)W1[(k0 + j) * 64 + col];
        *(half8*)(Bf1 + ((size_t)((kk * 4 + ct) * 64 + L)) * 8) = v;
    } else if (tid < 1024 + 384) {
        int u = tid - 1024;
        int kk = u / 192, rem = u % 192;
        int ct = rem >> 6, L = rem & 63;
        int k0 = kk * 32 + (L >> 4) * 8, col = ct * 16 + (L & 15);
        half8 v;
        #pragma unroll
        for (int j = 0; j < 8; j++)
            v[j] = (col < 40) ? (_Float16)W2[(k0 + j) * 40 + col] : (_Float16)0.f;
        *(half8*)(Bf2 + ((size_t)((kk * 3 + ct) * 64 + L)) * 8) = v;
    }
}

// ---------------- layer 1 node GEMM via MFMA: h1(fp16) = [x|topo] @ W1 ----------
// wave = 16 rows x 64 cols; block = 4 waves = 64 rows; grid 782
__global__ __launch_bounds__(256) void k_gemm1(
    const float* __restrict__ x, const float* __restrict__ topo,
    const _Float16* __restrict__ Bf1,
    const float* __restrict__ a_src, const float* __restrict__ a_dst,
    __half* __restrict__ h1, float* __restrict__ alsrc, float* __restrict__ aldst) {
    int wave = threadIdx.x >> 6, lane = threadIdx.x & 63;
    int row0 = blockIdx.x * 64 + wave * 16;
    if (row0 >= NN) return;
    int g = lane >> 4, li = lane & 15;
    int myrow = row0 + li;                        // A-operand row (m = lane&15)
    half8 B[16];
    const half8* bp = (const half8*)Bf1;
    #pragma unroll
    for (int i = 0; i < 16; i++) B[i] = bp[i * 64 + lane];
    floatx4 acc[4] = {{0,0,0,0},{0,0,0,0},{0,0,0,0},{0,0,0,0}};
    #pragma unroll
    for (int kk = 0; kk < 4; kk++) {
        int k0 = kk * 32 + g * 8;
        const float* sp = (k0 == 120) ? (topo + (size_t)myrow * 8)
                                      : (x + (size_t)myrow * 120 + k0);
        float4 u0 = ((const float4*)sp)[0];
        float4 u1 = ((const float4*)sp)[1];
        half8 av;
        av[0] = (_Float16)u0.x; av[1] = (_Float16)u0.y;
        av[2] = (_Float16)u0.z; av[3] = (_Float16)u0.w;
        av[4] = (_Float16)u1.x; av[5] = (_Float16)u1.y;
        av[6] = (_Float16)u1.z; av[7] = (_Float16)u1.w;
        #pragma unroll
        for (int ct = 0; ct < 4; ct++)
            acc[ct] = __builtin_amdgcn_mfma_f32_16x16x32_f16(av, B[kk * 4 + ct], acc[ct], 0, 0, 0);
    }
    // C layout: col = ct*16+li, row = row0 + 4*g + r
    #pragma unroll
    for (int ct = 0; ct < 4; ct++)
        #pragma unroll
        for (int r = 0; r < 4; r++)
            h1[(size_t)(row0 + 4 * g + r) * 64 + ct * 16 + li] = __float2half(acc[ct][r]);
    // attention logits: head = 2*ct + (li>>3), dim = li&7 (heads are 8-col aligned)
    float ps[4][4], pd[4][4];
    #pragma unroll
    for (int ct = 0; ct < 4; ct++) {
        int head = 2 * ct + (li >> 3), dix = li & 7;
        float asv = a_src[head * 8 + dix];
        float adv = a_dst[head * 8 + dix];
        #pragma unroll
        for (int r = 0; r < 4; r++) {
            ps[ct][r] = acc[ct][r] * asv;
            pd[ct][r] = acc[ct][r] * adv;
        }
    }
    #pragma unroll
    for (int off = 1; off <= 4; off <<= 1)
        #pragma unroll
        for (int ct = 0; ct < 4; ct++)
            #pragma unroll
            for (int r = 0; r < 4; r++) {
                ps[ct][r] += __shfl_xor(ps[ct][r], off, 64);
                pd[ct][r] += __shfl_xor(pd[ct][r], off, 64);
            }
    if ((li & 7) == 0) {
        #pragma unroll
        for (int ct = 0; ct < 4; ct++) {
            int head = 2 * ct + (li >> 3);
            #pragma unroll
            for (int r = 0; r < 4; r++) {
                int row = row0 + 4 * g + r;
                alsrc[row * 8 + head] = ps[ct][r];
                aldst[row * 8 + head] = pd[ct][r];
            }
        }
    }
}

// ------- layer 1 aggregation: wave/dst, 2 edges per iter (lane halves), fp16 vals
__global__ __launch_bounds__(256) void k_agg1(
    const int* __restrict__ rowstart, const int* __restrict__ srcs,
    const float* __restrict__ alsrc, const float* __restrict__ aldst,
    const __half* __restrict__ h1, const float* __restrict__ b1,
    __half* __restrict__ hout) {
    int wave = threadIdx.x >> 6;
    int lane = threadIdx.x & 63;
    int d = blockIdx.x * 4 + wave;
    if (d >= NN) return;
    int half = lane >> 5;        // which edge of the pair
    int cp = lane & 31;          // col pair: cols 2cp, 2cp+1
    int h = cp >> 2;             // head = (2cp)>>3
    float adst = aldst[d * 8 + h];
    int jb = rowstart[d], je = rowstart[d + 1];
    float ssum = 0.f;
    float ax = 0.f, ay = 0.f;
    int j = jb;
    for (; j + 8 <= je; j += 8) {
        int s0 = srcs[j + half], s1 = srcs[j + 2 + half];
        int s2 = srcs[j + 4 + half], s3 = srcs[j + 6 + half];
        float e0 = alsrc[s0 * 8 + h] + adst;
        float e1 = alsrc[s1 * 8 + h] + adst;
        float e2 = alsrc[s2 * 8 + h] + adst;
        float e3 = alsrc[s3 * 8 + h] + adst;
        __half2 v0 = *(const __half2*)(h1 + (size_t)s0 * 64 + 2 * cp);
        __half2 v1 = *(const __half2*)(h1 + (size_t)s1 * 64 + 2 * cp);
        __half2 v2 = *(const __half2*)(h1 + (size_t)s2 * 64 + 2 * cp);
        __half2 v3 = *(const __half2*)(h1 + (size_t)s3 * 64 + 2 * cp);
        float p0 = __expf(fmaxf(e0, 0.2f * e0));
        float p1 = __expf(fmaxf(e1, 0.2f * e1));
        float p2 = __expf(fmaxf(e2, 0.2f * e2));
        float p3 = __expf(fmaxf(e3, 0.2f * e3));
        float2 f0 = __half22float2(v0), f1 = __half22float2(v1);
        float2 f2 = __half22float2(v2), f3 = __half22float2(v3);
        ssum += (p0 + p1) + (p2 + p3);
        ax += p0 * f0.x + p1 * f1.x + p2 * f2.x + p3 * f3.x;
        ay += p0 * f0.y + p1 * f1.y + p2 * f2.y + p3 * f3.y;
    }
    for (; j < je; j += 2) {
        int e = j + half;
        bool valid = (e < je);
        int s = srcs[valid ? e : jb];
        float ea = alsrc[s * 8 + h] + adst;
        float p = valid ? __expf(fmaxf(ea, 0.2f * ea)) : 0.f;
        float2 f = __half22float2(*(const __half2*)(h1 + (size_t)s * 64 + 2 * cp));
        ssum += p;
        ax += p * f.x;
        ay += p * f.y;
    }
    ssum += __shfl_xor(ssum, 32, 64);
    ax += __shfl_xor(ax, 32, 64);
    ay += __shfl_xor(ay, 32, 64);
    if (half == 0) {
        float2 bv = *(const float2*)(b1 + 2 * cp);
        float inv = 1.f / ssum;
        float vx = ax * inv + bv.x;
        float vy = ay * inv + bv.y;
        vx = (vx > 0.f) ? vx : (__expf(vx) - 1.f);   // ELU
        vy = (vy > 0.f) ? vy : (__expf(vy) - 1.f);
        *(__half2*)(hout + (size_t)d * 64 + 2 * cp) = __floats2half2_rn(vx, vy);
    }
}

// ---------------- layer 2 node GEMM via MFMA (h2 fp16, 40 cols in 3 ctiles) -----
__global__ __launch_bounds__(256) void k_gemm2(
    const __half* __restrict__ hout, const _Float16* __restrict__ Bf2,
    const float* __restrict__ a_src2, const float* __restrict__ a_dst2,
    __half* __restrict__ h2, float* __restrict__ al2s, float* __restrict__ al2d) {
    int wave = threadIdx.x >> 6, lane = threadIdx.x & 63;
    int row0 = blockIdx.x * 64 + wave * 16;
    if (row0 >= NN) return;
    int g = lane >> 4, li = lane & 15;
    int myrow = row0 + li;
    half8 B[6];
    const half8* bp = (const half8*)Bf2;
    #pragma unroll
    for (int i = 0; i < 6; i++) B[i] = bp[i * 64 + lane];
    floatx4 acc[3] = {{0,0,0,0},{0,0,0,0},{0,0,0,0}};
    #pragma unroll
    for (int kk = 0; kk < 2; kk++) {
        int k0 = kk * 32 + g * 8;
        half8 av = *(const half8*)(hout + (size_t)myrow * 64 + k0);
        #pragma unroll
        for (int ct = 0; ct < 3; ct++)
            acc[ct] = __builtin_amdgcn_mfma_f32_16x16x32_f16(av, B[kk * 3 + ct], acc[ct], 0, 0, 0);
    }
    float ts[4] = {0.f, 0.f, 0.f, 0.f}, td[4] = {0.f, 0.f, 0.f, 0.f};
    #pragma unroll
    for (int ct = 0; ct < 3; ct++) {
        int col = ct * 16 + li;
        bool ok = (col < 40);
        float asv = ok ? a_src2[col] : 0.f;
        float adv = ok ? a_dst2[col] : 0.f;
        #pragma unroll
        for (int r = 0; r < 4; r++) {
            ts[r] += acc[ct][r] * asv;
            td[r] += acc[ct][r] * adv;
            if (ok) h2[(size_t)(row0 + 4 * g + r) * 40 + col] = __float2half(acc[ct][r]);
        }
    }
    #pragma unroll
    for (int off = 1; off <= 8; off <<= 1)
        #pragma unroll
        for (int r = 0; r < 4; r++) {
            ts[r] += __shfl_xor(ts[r], off, 64);
            td[r] += __shfl_xor(td[r], off, 64);
        }
    if (li == 0) {
        #pragma unroll
        for (int r = 0; r < 4; r++) {
            int row = row0 + 4 * g + r;
            al2s[row] = ts[r];
            al2d[row] = td[r];
        }
    }
}

// ------- layer 2 aggregation + fused log_softmax, 2 edges/iter, fp16 vals -------
__global__ __launch_bounds__(256) void k_agg2(
    const int* __restrict__ rowstart, const int* __restrict__ srcs,
    const float* __restrict__ al2s, const float* __restrict__ al2d,
    const __half* __restrict__ h2, const float* __restrict__ b2,
    float* __restrict__ out) {
    int wave = threadIdx.x >> 6;
    int lane = threadIdx.x & 63;
    int d = blockIdx.x * 4 + wave;
    if (d >= NN) return;
    int half = lane >> 5;
    int cp = lane & 31;              // cols 2cp,2cp+1; valid if cp<20
    bool act = (cp < 20);
    int cpc = act ? cp : 0;
    float adst = al2d[d];
    int jb = rowstart[d], je = rowstart[d + 1];
    float ssum = 0.f, ax = 0.f, ay = 0.f;
    int j = jb;
    for (; j + 8 <= je; j += 8) {
        int s0 = srcs[j + half], s1 = srcs[j + 2 + half];
        int s2 = srcs[j + 4 + half], s3 = srcs[j + 6 + half];
        float e0 = al2s[s0] + adst;
        float e1 = al2s[s1] + adst;
        float e2 = al2s[s2] + adst;
        float e3 = al2s[s3] + adst;
        __half2 v0 = *(const __half2*)(h2 + (size_t)s0 * 40 + 2 * cpc);
        __half2 v1 = *(const __half2*)(h2 + (size_t)s1 * 40 + 2 * cpc);
        __half2 v2 = *(const __half2*)(h2 + (size_t)s2 * 40 + 2 * cpc);
        __half2 v3 = *(const __half2*)(h2 + (size_t)s3 * 40 + 2 * cpc);
        float p0 = __expf(fmaxf(e0, 0.2f * e0));
        float p1 = __expf(fmaxf(e1, 0.2f * e1));
        float p2 = __expf(fmaxf(e2, 0.2f * e2));
        float p3 = __expf(fmaxf(e3, 0.2f * e3));
        float2 f0 = __half22float2(v0), f1 = __half22float2(v1);
        float2 f2 = __half22float2(v2), f3 = __half22float2(v3);
        ssum += (p0 + p1) + (p2 + p3);
        ax += p0 * f0.x + p1 * f1.x + p2 * f2.x + p3 * f3.x;
        ay += p0 * f0.y + p1 * f1.y + p2 * f2.y + p3 * f3.y;
    }
    for (; j < je; j += 2) {
        int e = j + half;
        bool valid = (e < je);
        int s = srcs[valid ? e : jb];
        float ea = al2s[s] + adst;
        float p = valid ? __expf(fmaxf(ea, 0.2f * ea)) : 0.f;
        float2 f = __half22float2(*(const __half2*)(h2 + (size_t)s * 40 + 2 * cpc));
        ssum += p;
        ax += p * f.x;
        ay += p * f.y;
    }
    ssum += __shfl_xor(ssum, 32, 64);
    ax += __shfl_xor(ax, 32, 64);
    ay += __shfl_xor(ay, 32, 64);
    float inv = 1.f / ssum;
    float2 bv = *(const float2*)(b2 + 2 * cpc);
    float ox = ax * inv + bv.x;
    float oy = ay * inv + bv.y;
    float mo = act ? fmaxf(ox, oy) : -3.0e38f;
    #pragma unroll
    for (int off = 16; off; off >>= 1) mo = fmaxf(mo, __shfl_xor(mo, off, 64));
    float te = act ? (__expf(ox - mo) + __expf(oy - mo)) : 0.f;
    #pragma unroll
    for (int off = 16; off; off >>= 1) te += __shfl_xor(te, off, 64);
    float ls = __logf(te);
    if (act && half == 0)
        *(float2*)(out + (size_t)d * 40 + 2 * cp) = make_float2(ox - mo - ls, oy - mo - ls);
}

extern "C" void kernel_launch(void* const* d_in, const int* in_sizes, int n_in,
                              void* d_out, int out_size, void* d_ws, size_t ws_size,
                              hipStream_t stream) {
    (void)in_sizes; (void)n_in; (void)out_size; (void)ws_size;
    const float* x    = (const float*)d_in[0];
    const float* topo = (const float*)d_in[1];
    const int*   ei   = (const int*)d_in[2];
    const float* W1   = (const float*)d_in[3];
    const float* as1  = (const float*)d_in[4];
    const float* ad1  = (const float*)d_in[5];
    const float* b1   = (const float*)d_in[6];
    const float* W2   = (const float*)d_in[7];
    const float* as2  = (const float*)d_in[8];
    const float* ad2  = (const float*)d_in[9];
    const float* b2   = (const float*)d_in[10];
    float* out = (float*)d_out;

    char* ws = (char*)d_ws;
    size_t off = 0;
    auto alloc = [&](size_t bytes) {
        void* p = ws + off;
        off += (bytes + 255) / 256 * 256;
        return p;
    };
    int*       rowstart   = (int*)alloc((NN + 1) * 4);
    int*       cursor     = (int*)alloc(NBUCK * 4);
    int*       bucketOut  = (int*)alloc(NBUCK * 4);
    unsigned*  bucketData = (unsigned*)alloc((size_t)NBUCK * CAP * 4);
    int*       srcs       = (int*)alloc(ET * 4);
    float*     alsrc1     = (float*)alloc((size_t)NN * 8 * 4);
    float*     aldst1     = (float*)alloc((size_t)NN * 8 * 4);
    float*     al2s       = (float*)alloc(NN * 4);
    float*     al2d       = (float*)alloc(NN * 4);
    _Float16*  Bf1        = (_Float16*)alloc(4 * 4 * 64 * 8 * 2);
    _Float16*  Bf2        = (_Float16*)alloc(2 * 3 * 64 * 8 * 2);
    __half*    h1         = (__half*)alloc((size_t)NN * 64 * 2);
    __half*    hout       = (__half*)alloc((size_t)NN * 64 * 2);
    __half*    h2         = h1;   // alias: h1 dead after k_agg1 (4 MB <= 6.4 MB)

    k_zero    <<<1,     256, 0, stream>>>(cursor);
    k_prep    <<<6,     256, 0, stream>>>(W1, W2, Bf1, Bf2);
    k_bucketA <<<NBA,   256, 0, stream>>>(ei, cursor, bucketData);
    k_scanB   <<<1,     256, 0, stream>>>(cursor, bucketOut, rowstart);
    k_bucketB <<<NBUCK, 256, 0, stream>>>(bucketData, cursor, bucketOut, rowstart, srcs);
    k_gemm1   <<<NGB,   256, 0, stream>>>(x, topo, Bf1, as1, ad1, h1, alsrc1, aldst1);
    k_agg1    <<<(NN + 3) / 4, 256, 0, stream>>>(rowstart, srcs, alsrc1, aldst1, h1, b1, hout);
    k_gemm2   <<<NGB,   256, 0, stream>>>(hout, Bf2, as2, ad2, h2, al2s, al2d);
    k_agg2    <<<(NN + 3) / 4, 256, 0, stream>>>(rowstart, srcs, al2s, al2d, h2, b2, out);
}